// Round 1
// baseline (118.275 us; speedup 1.0000x reference)
//
#include <hip/hip_runtime.h>
#include <hip/hip_bf16.h>

// PtrNet2: B=512, T=2048, IN=2, H=128
// Algebraic collapse: ref and u2 are rank-2 affine maps of (x0, x1) since IN=2.
//   M0 = enc_W @ emb_W[:,0]; M1 = enc_W @ emb_W[:,1]; c = enc_W @ emb_b + enc_b
//   ref[b,t,h]  = mask*(x0*M0[h] + x1*M1[h] + c[h])
//   P0 = Wref_W@M0; P1 = Wref_W@M1; E = Wref_W@c
//   u2[b,h,t]   = mask*(x0*P0[h] + x1*P1[h] + E[h]) + Wref_b[h]
//   glimpse out = X0*P0 + X1*P1 + C*E + Wref_b,  X0=sum a*m*x0, X1=sum a*m*x1, C=sum a*m
// Heavy part: u[b,t] = sum_h Vec[h]*tanh(u1[b,h] + u2[b,h,t])  (B*T*H tanh, x2 glimpses)

#define Bsz 512
#define Tsz 2048
#define Hsz 128

__device__ __forceinline__ float tanh_fast(float v) {
    float ex = __expf(2.f * v);
    return fmaf(-2.f, __builtin_amdgcn_rcpf(ex + 1.f), 1.f);
}

// ---- precompute P0, P1, E (one block, 128 threads) ----
__global__ __launch_bounds__(128) void kprep(
        const float* __restrict__ embW, const float* __restrict__ embB,
        const float* __restrict__ encW, const float* __restrict__ encB,
        const float* __restrict__ wrefW,
        float* __restrict__ P0, float* __restrict__ P1, float* __restrict__ E) {
    __shared__ float m0[Hsz], m1[Hsz], cc[Hsz];
    int h = threadIdx.x;
    float a0 = 0.f, a1 = 0.f, ac = 0.f;
    for (int k = 0; k < Hsz; ++k) {
        float w = encW[h * Hsz + k];
        a0 = fmaf(w, embW[k * 2 + 0], a0);
        a1 = fmaf(w, embW[k * 2 + 1], a1);
        ac = fmaf(w, embB[k], ac);
    }
    m0[h] = a0; m1[h] = a1; cc[h] = ac + encB[h];
    __syncthreads();
    float p0 = 0.f, p1 = 0.f, pe = 0.f;
    for (int k = 0; k < Hsz; ++k) {
        float w = wrefW[h * Hsz + k];
        p0 = fmaf(w, m0[k], p0);
        p1 = fmaf(w, m1[k], p1);
        pe = fmaf(w, cc[k], pe);
    }
    P0[h] = p0; P1[h] = p1; E[h] = pe;
}

// ---- u1[b,h] = Wq_W[h,:] . query_b + Wq_b[h] ; query from dec (mode 0) or trip (mode 1)
__global__ __launch_bounds__(128) void kquery(
        const float* __restrict__ wqW, const float* __restrict__ wqB,
        const float* __restrict__ dec,
        const float* __restrict__ P0, const float* __restrict__ P1,
        const float* __restrict__ E, const float* __restrict__ wrefB,
        const float* __restrict__ trip, int mode,
        float* __restrict__ u1) {
    __shared__ float q[Hsz];
    int b = blockIdx.x, h = threadIdx.x;
    if (mode == 0) {
        q[h] = dec[h];
    } else {
        float4 tv = ((const float4*)trip)[b];  // X0, X1, C, -
        q[h] = fmaf(tv.x, P0[h], fmaf(tv.y, P1[h], fmaf(tv.z, E[h], wrefB[h])));
    }
    __syncthreads();
    float acc = wqB[h];
    const float* wr = wqW + (size_t)h * Hsz;
    #pragma unroll 8
    for (int k = 0; k < Hsz; ++k) acc = fmaf(wr[k], q[k], acc);
    u1[b * Hsz + h] = acc;
}

// ---- u[b,t] = sum_h Vec[h]*tanh(base[h] + m*(x0*P0[h]+x1*P1[h]+E[h])), base = u1+wrefB
__global__ __launch_bounds__(256) void kscore(
        const float* __restrict__ x, const float* __restrict__ mask,
        const float* __restrict__ P0, const float* __restrict__ P1,
        const float* __restrict__ E, const float* __restrict__ wrefB,
        const float* __restrict__ vec, const float* __restrict__ u1,
        float* __restrict__ u) {
    __shared__ float4 coef[Hsz];  // {P0, P1, E, u1+wrefB}
    __shared__ float vls[Hsz];
    int b = blockIdx.x >> 3, tile = blockIdx.x & 7;
    int tid = threadIdx.x;  // 256 threads -> 256 tokens
    if (tid < Hsz) {
        coef[tid] = make_float4(P0[tid], P1[tid], E[tid], u1[b * Hsz + tid] + wrefB[tid]);
        vls[tid] = vec[tid];
    }
    __syncthreads();
    size_t idx = (size_t)b * Tsz + tile * 256 + tid;
    float2 xv = ((const float2*)x)[idx];
    float m = mask[idx];
    float xm0 = xv.x * m, xm1 = xv.y * m;
    float acc = 0.f;
    #pragma unroll 8
    for (int h = 0; h < Hsz; ++h) {
        float4 cf = coef[h];
        float val = fmaf(xm0, cf.x, fmaf(xm1, cf.y, fmaf(m, cf.z, cf.w)));
        acc = fmaf(vls[h], tanh_fast(val), acc);
    }
    u[idx] = acc;
}

// ---- softmax over t (stable) + attention statistics X0, X1, C per b ----
__global__ __launch_bounds__(256) void ksoftstat(
        const float* __restrict__ u, const float* __restrict__ x,
        const float* __restrict__ mask, float* __restrict__ trip) {
    int b = blockIdx.x, tid = threadIdx.x;  // 256 threads, 4 waves; 8 tokens/thread
    const float4* u4 = (const float4*)(u + (size_t)b * Tsz);
    float4 ua = u4[tid * 2], ub = u4[tid * 2 + 1];
    float m = fmaxf(fmaxf(fmaxf(ua.x, ua.y), fmaxf(ua.z, ua.w)),
                    fmaxf(fmaxf(ub.x, ub.y), fmaxf(ub.z, ub.w)));
    for (int off = 32; off; off >>= 1) m = fmaxf(m, __shfl_xor(m, off));
    __shared__ float wred[4];
    __shared__ float4 wsum[4];
    int wave = tid >> 6, lane = tid & 63;
    if (lane == 0) wred[wave] = m;
    __syncthreads();
    m = fmaxf(fmaxf(wred[0], wred[1]), fmaxf(wred[2], wred[3]));

    const float4* m4 = (const float4*)(mask + (size_t)b * Tsz);
    float4 ma = m4[tid * 2], mb = m4[tid * 2 + 1];
    const float4* x4 = (const float4*)(x + (size_t)b * (Tsz * 2));
    float4 xa = x4[tid * 4], xb = x4[tid * 4 + 1], xc = x4[tid * 4 + 2], xd = x4[tid * 4 + 3];
    float e0 = __expf(ua.x - m), e1 = __expf(ua.y - m), e2 = __expf(ua.z - m), e3 = __expf(ua.w - m);
    float e4 = __expf(ub.x - m), e5 = __expf(ub.y - m), e6 = __expf(ub.z - m), e7 = __expf(ub.w - m);
    float Z = ((e0 + e1) + (e2 + e3)) + ((e4 + e5) + (e6 + e7));
    float em0 = e0 * ma.x, em1 = e1 * ma.y, em2 = e2 * ma.z, em3 = e3 * ma.w;
    float em4 = e4 * mb.x, em5 = e5 * mb.y, em6 = e6 * mb.z, em7 = e7 * mb.w;
    float Sm = ((em0 + em1) + (em2 + em3)) + ((em4 + em5) + (em6 + em7));
    float S0 = em0 * xa.x + em1 * xa.z + em2 * xb.x + em3 * xb.z
             + em4 * xc.x + em5 * xc.z + em6 * xd.x + em7 * xd.z;
    float S1 = em0 * xa.y + em1 * xa.w + em2 * xb.y + em3 * xb.w
             + em4 * xc.y + em5 * xc.w + em6 * xd.y + em7 * xd.w;
    for (int off = 32; off; off >>= 1) {
        Z  += __shfl_xor(Z, off);
        Sm += __shfl_xor(Sm, off);
        S0 += __shfl_xor(S0, off);
        S1 += __shfl_xor(S1, off);
    }
    if (lane == 0) wsum[wave] = make_float4(Z, Sm, S0, S1);
    __syncthreads();
    if (tid == 0) {
        float Zt  = wsum[0].x + wsum[1].x + wsum[2].x + wsum[3].x;
        float Smt = wsum[0].y + wsum[1].y + wsum[2].y + wsum[3].y;
        float S0t = wsum[0].z + wsum[1].z + wsum[2].z + wsum[3].z;
        float S1t = wsum[0].w + wsum[1].w + wsum[2].w + wsum[3].w;
        float inv = 1.f / Zt;
        ((float4*)trip)[b] = make_float4(S0t * inv, S1t * inv, Smt * inv, 0.f);
    }
}

// ---- final head: pred[b,o] = sum_h fc2[o,h]*relu(fc1[h,:] . query_b) ----
__global__ __launch_bounds__(128) void kfinal(
        const float* __restrict__ P0, const float* __restrict__ P1,
        const float* __restrict__ E, const float* __restrict__ wrefB,
        const float* __restrict__ trip,
        const float* __restrict__ fc1, const float* __restrict__ fc2,
        float* __restrict__ out) {
    __shared__ float q[Hsz];
    __shared__ float r[Hsz];
    int b = blockIdx.x, tid = threadIdx.x;  // 128 threads = 2 waves
    float4 tv = ((const float4*)trip)[b];
    q[tid] = fmaf(tv.x, P0[tid], fmaf(tv.y, P1[tid], fmaf(tv.z, E[tid], wrefB[tid])));
    __syncthreads();
    float acc = 0.f;
    const float* fr = fc1 + (size_t)tid * Hsz;
    #pragma unroll 8
    for (int k = 0; k < Hsz; ++k) acc = fmaf(fr[k], q[k], acc);
    r[tid] = fmaxf(acc, 0.f);
    __syncthreads();
    int o = tid >> 6, lane = tid & 63;
    float s = fc2[o * Hsz + lane] * r[lane] + fc2[o * Hsz + lane + 64] * r[lane + 64];
    for (int off = 32; off; off >>= 1) s += __shfl_xor(s, off);
    if (lane == 0) out[b * 2 + o] = s;
}

extern "C" void kernel_launch(void* const* d_in, const int* in_sizes, int n_in,
                              void* d_out, int out_size, void* d_ws, size_t ws_size,
                              hipStream_t stream) {
    const float* x     = (const float*)d_in[0];
    const float* mask  = (const float*)d_in[1];
    const float* embW  = (const float*)d_in[2];
    const float* embB  = (const float*)d_in[3];
    const float* encW  = (const float*)d_in[4];
    const float* encB  = (const float*)d_in[5];
    const float* dec   = (const float*)d_in[6];
    const float* vec   = (const float*)d_in[7];
    const float* wqW   = (const float*)d_in[8];
    const float* wqB   = (const float*)d_in[9];
    const float* wrefW = (const float*)d_in[10];
    const float* wrefB = (const float*)d_in[11];
    const float* fc1   = (const float*)d_in[12];
    const float* fc2   = (const float*)d_in[13];

    float* ws   = (float*)d_ws;
    float* P0   = ws;            // 128
    float* P1   = ws + 128;      // 128
    float* E    = ws + 256;      // 128 (pad to 512)
    float* u1   = ws + 512;      // B*H = 65536
    float* u    = ws + 66048;    // B*T = 1048576
    float* trip = ws + 1114624;  // B*4 = 2048
    float* out  = (float*)d_out;

    kprep<<<1, 128, 0, stream>>>(embW, embB, encW, encB, wrefW, P0, P1, E);
    for (int g = 0; g < 2; ++g) {
        kquery<<<Bsz, 128, 0, stream>>>(wqW, wqB, dec, P0, P1, E, wrefB, trip, g, u1);
        kscore<<<Bsz * (Tsz / 256), 256, 0, stream>>>(x, mask, P0, P1, E, wrefB, vec, u1, u);
        ksoftstat<<<Bsz, 256, 0, stream>>>(u, x, mask, trip);
    }
    kfinal<<<Bsz, 128, 0, stream>>>(P0, P1, E, wrefB, trip, fc1, fc2, out);
}

// Round 2
// 84.573 us; speedup vs baseline: 1.3985x; 1.3985x over previous
//
#include <hip/hip_runtime.h>
#include <hip/hip_bf16.h>

// PtrNet2: B=512, T=2048, IN=2, H=128
// Full algebraic collapse (IN=2):
//   ref[b,t,h] = mask*(x0*M0[h] + x1*M1[h] + c[h]),  M0=enc_W@emb_W[:,0], etc.
//   u2[b,h,t]  = mask*(x0*P0[h] + x1*P1[h] + E[h]) + wrefB[h],  P*=Wref_W@M*
//   glimpse    = X0*P0 + X1*P1 + C*E + wrefB,  X0=sum a*m*x0, X1=sum a*m*x1, C=sum a*m
// tanh fold: sum_h vec*tanh(v_h) = Vsum - sum_h (2vec_h)*rcp(exp2(c*v_h)+1), c=2*log2(e).
// Vsum cancels in softmax: u = Vsum - acc  =>  weights = exp(accmin - acc).
// Glimpse-0 query is batch-uniform => its u1 is precomputed in kprep.
// One block per batch row does: score -> softmax/stats -> u1 matvec -> score -> stats -> FC head.

#define Bsz 512
#define Tsz 2048
#define Hsz 128
#define TPB 512
#define TOK 4  // Tsz / TPB

#define C2LOG2E 2.8853900817779268f
#define LOG2E   1.4426950408889634f

__device__ __forceinline__ float exp2fast(float x) { return __builtin_amdgcn_exp2f(x); }
__device__ __forceinline__ float rcpfast(float x)  { return __builtin_amdgcn_rcpf(x); }

// ---- kprep: SC={c*P0, c*P1, c*E, c*(u1g0+wrefB)}, UC={P0,P1,E,wrefB}, V2=2*vec ----
__global__ __launch_bounds__(128) void kprep(
        const float* __restrict__ embW, const float* __restrict__ embB,
        const float* __restrict__ encW, const float* __restrict__ encB,
        const float* __restrict__ wrefW, const float* __restrict__ wrefB,
        const float* __restrict__ wqW, const float* __restrict__ wqB,
        const float* __restrict__ dec, const float* __restrict__ vec,
        float4* __restrict__ SC, float4* __restrict__ UC, float* __restrict__ V2) {
    __shared__ float m0[Hsz], m1[Hsz], cc[Hsz], dq[Hsz];
    int h = threadIdx.x;
    float a0 = 0.f, a1 = 0.f, ac = 0.f;
    for (int k = 0; k < Hsz; ++k) {
        float w = encW[h * Hsz + k];
        a0 = fmaf(w, embW[2 * k + 0], a0);
        a1 = fmaf(w, embW[2 * k + 1], a1);
        ac = fmaf(w, embB[k], ac);
    }
    m0[h] = a0; m1[h] = a1; cc[h] = ac + encB[h]; dq[h] = dec[h];
    __syncthreads();
    float p0 = 0.f, p1 = 0.f, pe = 0.f, uq = wqB[h];
    for (int k = 0; k < Hsz; ++k) {
        float w = wrefW[h * Hsz + k];
        p0 = fmaf(w, m0[k], p0);
        p1 = fmaf(w, m1[k], p1);
        pe = fmaf(w, cc[k], pe);
        uq = fmaf(wqW[h * Hsz + k], dq[k], uq);
    }
    float wb = wrefB[h];
    SC[h] = make_float4(C2LOG2E * p0, C2LOG2E * p1, C2LOG2E * pe, C2LOG2E * (uq + wb));
    UC[h] = make_float4(p0, p1, pe, wb);
    V2[h] = 2.f * vec[h];
}

// ---- fused: one block per batch row, both glimpses + final head ----
__global__ __launch_bounds__(TPB) void kfused(
        const float* __restrict__ x, const float* __restrict__ mask,
        const float4* __restrict__ SC, const float4* __restrict__ UC,
        const float* __restrict__ V2,
        const float* __restrict__ wqW, const float* __restrict__ wqB,
        const float* __restrict__ fc1, const float* __restrict__ fc2,
        float* __restrict__ out) {
    __shared__ float4 cf[Hsz];   // {c*P0, c*P1, c*E, c*(u1+wrefB)} — .w updated for glimpse 2
    __shared__ float4 uc[Hsz];   // {P0, P1, E, wrefB}
    __shared__ float v2s[Hsz];
    __shared__ float q[Hsz], rr[Hsz];
    __shared__ float pp[4][Hsz];
    __shared__ float redm[8];
    __shared__ float4 red4[8];
    __shared__ float4 tripS;

    int b = blockIdx.x, tid = threadIdx.x;
    int wave = tid >> 6, lane = tid & 63;
    if (tid < Hsz) { cf[tid] = SC[tid]; uc[tid] = UC[tid]; v2s[tid] = V2[tid]; }

    float2 xv[TOK]; float mk[TOK];
    const float2* x2 = (const float2*)(x + (size_t)b * Tsz * 2);
    const float* mrow = mask + (size_t)b * Tsz;
    #pragma unroll
    for (int j = 0; j < TOK; ++j) { xv[j] = x2[j * TPB + tid]; mk[j] = mrow[j * TPB + tid]; }
    __syncthreads();

    float X0 = 0.f, X1 = 0.f, Cm = 0.f;
    #pragma unroll 1
    for (int g = 0; g < 2; ++g) {
        // ---- score: acc[j] = sum_h (2vec_h)*rcp(exp2(arg)+1);  u = Vsum - acc ----
        float acc[TOK];
        #pragma unroll
        for (int j = 0; j < TOK; ++j) acc[j] = 0.f;
        for (int h = 0; h < Hsz; ++h) {
            float4 cv = cf[h]; float vv = v2s[h];
            #pragma unroll
            for (int j = 0; j < TOK; ++j) {
                float w = fmaf(xv[j].x, cv.x, fmaf(xv[j].y, cv.y, cv.z));
                float a = fmaf(mk[j], w, cv.w);
                float r = rcpfast(exp2fast(a) + 1.f);
                acc[j] = fmaf(vv, r, acc[j]);
            }
        }
        // ---- softmax weights: exp(accmin - acc); block min-reduce ----
        float am = fminf(fminf(acc[0], acc[1]), fminf(acc[2], acc[3]));
        for (int off = 32; off; off >>= 1) am = fminf(am, __shfl_xor(am, off));
        if (lane == 0) redm[wave] = am;
        __syncthreads();
        am = redm[0];
        #pragma unroll
        for (int w2 = 1; w2 < 8; ++w2) am = fminf(am, redm[w2]);
        // ---- stats: Z, Sm, S0, S1 ----
        float Z = 0.f, Sm = 0.f, S0 = 0.f, S1 = 0.f;
        #pragma unroll
        for (int j = 0; j < TOK; ++j) {
            float e = exp2fast((am - acc[j]) * LOG2E);
            float em = e * mk[j];
            Z += e; Sm += em;
            S0 = fmaf(em, xv[j].x, S0);
            S1 = fmaf(em, xv[j].y, S1);
        }
        for (int off = 32; off; off >>= 1) {
            Z += __shfl_xor(Z, off); Sm += __shfl_xor(Sm, off);
            S0 += __shfl_xor(S0, off); S1 += __shfl_xor(S1, off);
        }
        if (lane == 0) red4[wave] = make_float4(Z, Sm, S0, S1);
        __syncthreads();
        if (tid == 0) {
            float Zt = 0.f, Smt = 0.f, S0t = 0.f, S1t = 0.f;
            #pragma unroll
            for (int w2 = 0; w2 < 8; ++w2) {
                Zt += red4[w2].x; Smt += red4[w2].y; S0t += red4[w2].z; S1t += red4[w2].w;
            }
            float inv = 1.f / Zt;
            tripS = make_float4(S0t * inv, S1t * inv, Smt * inv, 0.f);
        }
        __syncthreads();
        X0 = tripS.x; X1 = tripS.y; Cm = tripS.z;

        if (g == 0) {
            // ---- glimpse-1 query + u1 matvec; update cf[h].w ----
            if (tid < Hsz) {
                float4 u4 = uc[tid];
                q[tid] = fmaf(X0, u4.x, fmaf(X1, u4.y, fmaf(Cm, u4.z, u4.w)));
            }
            __syncthreads();
            {
                int h = tid & (Hsz - 1), part = tid >> 7;   // 4 parts x 32 k
                float s = 0.f;
                const float* wr = wqW + (size_t)h * Hsz + part * 32;
                #pragma unroll 8
                for (int k = 0; k < 32; ++k) s = fmaf(wr[k], q[part * 32 + k], s);
                pp[part][h] = s;
            }
            __syncthreads();
            if (tid < Hsz) {
                float u1h = wqB[tid] + ((pp[0][tid] + pp[1][tid]) + (pp[2][tid] + pp[3][tid]));
                float4 c4 = cf[tid];
                c4.w = C2LOG2E * (u1h + uc[tid].w);
                cf[tid] = c4;
            }
            __syncthreads();
        }
    }
    // ---- final head: q2 -> relu(fc1 q2) -> fc2 ----
    if (tid < Hsz) {
        float4 u4 = uc[tid];
        q[tid] = fmaf(X0, u4.x, fmaf(X1, u4.y, fmaf(Cm, u4.z, u4.w)));
    }
    __syncthreads();
    {
        int h = tid & (Hsz - 1), part = tid >> 7;
        float s = 0.f;
        const float* fr = fc1 + (size_t)h * Hsz + part * 32;
        #pragma unroll 8
        for (int k = 0; k < 32; ++k) s = fmaf(fr[k], q[part * 32 + k], s);
        pp[part][h] = s;
    }
    __syncthreads();
    if (tid < Hsz) {
        rr[tid] = fmaxf(0.f, (pp[0][tid] + pp[1][tid]) + (pp[2][tid] + pp[3][tid]));
    }
    __syncthreads();
    if (tid < 128) {
        int o = tid >> 6, l = tid & 63;
        float s = fc2[o * Hsz + l] * rr[l] + fc2[o * Hsz + 64 + l] * rr[64 + l];
        for (int off = 32; off; off >>= 1) s += __shfl_xor(s, off);
        if (l == 0) out[b * 2 + o] = s;
    }
}

extern "C" void kernel_launch(void* const* d_in, const int* in_sizes, int n_in,
                              void* d_out, int out_size, void* d_ws, size_t ws_size,
                              hipStream_t stream) {
    const float* x     = (const float*)d_in[0];
    const float* mask  = (const float*)d_in[1];
    const float* embW  = (const float*)d_in[2];
    const float* embB  = (const float*)d_in[3];
    const float* encW  = (const float*)d_in[4];
    const float* encB  = (const float*)d_in[5];
    const float* dec   = (const float*)d_in[6];
    const float* vec   = (const float*)d_in[7];
    const float* wqW   = (const float*)d_in[8];
    const float* wqB   = (const float*)d_in[9];
    const float* wrefW = (const float*)d_in[10];
    const float* wrefB = (const float*)d_in[11];
    const float* fc1   = (const float*)d_in[12];
    const float* fc2   = (const float*)d_in[13];

    float* ws = (float*)d_ws;
    float4* SC = (float4*)ws;            // 128 float4
    float4* UC = (float4*)(ws + 512);    // 128 float4
    float* V2  = ws + 1024;              // 128 floats
    float* out = (float*)d_out;

    kprep<<<1, 128, 0, stream>>>(embW, embB, encW, encB, wrefW, wrefB, wqW, wqB,
                                 dec, vec, SC, UC, V2);
    kfused<<<Bsz, TPB, 0, stream>>>(x, mask, SC, UC, V2, wqW, wqB, fc1, fc2, out);
}